// Round 10
// baseline (2244.307 us; speedup 1.0000x reference)
//
#include <hip/hip_runtime.h>

#define IDIM 512
#define MIXD 32
#define HID 96
#define BB 256
#define TT 512

typedef float f32x2 __attribute__((ext_vector_type(2)));
typedef float f32x4 __attribute__((ext_vector_type(4)));

// v_exp_f32: D = 2^S0
#define EXP2(x) __builtin_amdgcn_exp2f(x)

// DPP row_shl:N add on the VALU pipe (not the shared LDS pipe).
template <int CTRL>
__device__ __forceinline__ float dpp_shl_add(float x) {
    int m = __builtin_amdgcn_update_dpp(0, __float_as_int(x), CTRL, 0xf, 0xf, true);
    return x + __int_as_float(m);
}
// Reduce 8 consecutive lanes (octet) into the octet's lane 0.
__device__ __forceinline__ float octet_reduce_lane0(float x) {
    x = dpp_shl_add<0x104>(x);   // row_shl:4
    x = dpp_shl_add<0x102>(x);   // row_shl:2
    x = dpp_shl_add<0x101>(x);   // row_shl:1
    return x;
}

// ---------------- fused mix + GRU scan + head: 1 batch element per block ----
// 512 threads = 8 waves (2/SIMD).
//   waves 0-3 (tid<256): CONSUMER — exact R9 scan structure (octet per j0,
//     3 j's per octet, DPP reduce, h ping-pong, 1 barrier/step).
//   waves 4-7: PRODUCER — z = W_mix·x computed on the fly into the LDS chunk
//     buffer. Thread (pm=p>>3, pks=p&7) owns W_mix[pm, 64pks:64pks+64) in 64
//     VGPRs; per step it loads one x-row slice, 32 pk_fma, octet DPP reduce,
//     lane pks==0 writes sz[(c+1)&1][tt][pm]. z NEVER touches global memory
//     and the separate k_mix launch (~145 us) disappears into the scan's
//     idle issue/latency slots (step budget 1290 cy >> producer 750 cy).
// Chunk 0 is made in a barrier-free prologue by ALL 512 threads (consumers
// use a temp W slice that dies before scan weights load -> no reg overlap).
__global__ __launch_bounds__(512, 2) void k_fused(const float* __restrict__ x,
                                                  const float* __restrict__ Wmix,
                                                  const float* __restrict__ Wih,
                                                  const float* __restrict__ Whh,
                                                  const float* __restrict__ bih,
                                                  const float* __restrict__ bhh,
                                                  const float* __restrict__ Whead,
                                                  const float* __restrict__ bhead,
                                                  float* __restrict__ y) {
    const int b    = blockIdx.x;
    const int tid  = threadIdx.x;
    const bool cons = tid < 256;
    const float L  = 1.4426950408889634f;   // log2(e)
    const float L2 = 2.8853900817779268f;   // 2*log2(e)

    __shared__ __align__(16) float sz[2][256 * MIXD];  // 64 KB z chunk dbuf
    __shared__ __align__(16) float shp[2][HID];        // h ping-pong
    __shared__ __align__(16) float szn[MIXD];

    // ---- mix W slice (persistent for producers; prologue-only for consumers)
    const int p  = tid & 255;
    const int pm = p >> 3, pks = p & 7;
    f32x2 wp[32];
    #pragma unroll
    for (int u = 0; u < 16; ++u) {
        f32x4 v = *(const f32x4*)(Wmix + (size_t)pm * IDIM + 64 * pks + 4 * u);
        wp[2*u] = v.xy; wp[2*u+1] = v.zw;
    }

    if (tid < HID) shp[0][tid] = 0.f;   // h0 = 0 (visible after prologue barrier)

    // ---- prologue: produce chunk 0 (t=0..255); consumers rows 0..127,
    //      producers rows 128..255; depth-1 x prefetch, no barriers inside.
    {
        const int r0 = cons ? 0 : 128;
        const float* xb = x + (size_t)b * TT * IDIM + 64 * pks;
        f32x4 xv[16], xn[16];
        #pragma unroll
        for (int u = 0; u < 16; ++u)
            xv[u] = *(const f32x4*)(xb + (size_t)r0 * IDIM + 4 * u);
        for (int rr = 0; rr < 128; ++rr) {
            if (rr + 1 < 128) {
                #pragma unroll
                for (int u = 0; u < 16; ++u)
                    xn[u] = *(const f32x4*)(xb + (size_t)(r0 + rr + 1) * IDIM + 4 * u);
            }
            f32x2 acc = {0.f, 0.f};
            #pragma unroll
            for (int u = 0; u < 16; ++u) {
                acc = __builtin_elementwise_fma(wp[2*u],   xv[u].xy, acc);
                acc = __builtin_elementwise_fma(wp[2*u+1], xv[u].zw, acc);
            }
            float s = octet_reduce_lane0(acc.x + acc.y);
            if (pks == 0) sz[0][(r0 + rr) * MIXD + pm] = s;
            #pragma unroll
            for (int u = 0; u < 16; ++u) xv[u] = xn[u];
        }
    }

    // ---- consumer scan weights (loaded AFTER prologue: keeps reg peak low;
    //      wp stays live only on producer waves)
    const int j0 = tid >> 3;      // 0..31 (consumers)
    const int o  = tid & 7;
    f32x2 whr[3][6], whu[3][6], whn[3][6], wir[3][2], wiu[3][2], win[3][2];
    float br[3], bu[3], bxn[3], bhn[3];
    float hown[3] = {0.f, 0.f, 0.f};
    if (cons) {
        #pragma unroll
        for (int i = 0; i < 3; ++i) {
            const int j = j0 + 32 * i;
            #pragma unroll
            for (int c = 0; c < 3; ++c) {
                f32x4 v = *(const f32x4*)(Whh + (size_t)(j        ) * HID + o * 12 + c * 4);
                v *= L;  whr[i][2*c] = v.xy; whr[i][2*c+1] = v.zw;
            }
            #pragma unroll
            for (int c = 0; c < 3; ++c) {
                f32x4 v = *(const f32x4*)(Whh + (size_t)(j +   HID) * HID + o * 12 + c * 4);
                v *= L;  whu[i][2*c] = v.xy; whu[i][2*c+1] = v.zw;
            }
            #pragma unroll
            for (int c = 0; c < 3; ++c) {
                f32x4 v = *(const f32x4*)(Whh + (size_t)(j + 2*HID) * HID + o * 12 + c * 4);
                v *= L2; whn[i][2*c] = v.xy; whn[i][2*c+1] = v.zw;
            }
            {
                f32x4 v = *(const f32x4*)(Wih + (size_t)(j        ) * MIXD + o * 4);
                v *= L;  wir[i][0] = v.xy; wir[i][1] = v.zw;
            }
            {
                f32x4 v = *(const f32x4*)(Wih + (size_t)(j +   HID) * MIXD + o * 4);
                v *= L;  wiu[i][0] = v.xy; wiu[i][1] = v.zw;
            }
            {
                f32x4 v = *(const f32x4*)(Wih + (size_t)(j + 2*HID) * MIXD + o * 4);
                v *= L2; win[i][0] = v.xy; win[i][1] = v.zw;
            }
            br[i]  = (o == 0) ? L  * (bih[j]       + bhh[j])       : 0.f;
            bu[i]  = (o == 0) ? L  * (bih[j + HID] + bhh[j + HID]) : 0.f;
            bxn[i] = (o == 0) ? L2 * bih[j + 2*HID] : 0.f;
            bhn[i] = (o == 0) ? L2 * bhh[j + 2*HID] : 0.f;
        }
    }
    __syncthreads();   // chunk 0 + h0 visible

    // ---- main loop: 2 chunks x 256 steps, one barrier per step ----
    for (int c = 0; c < 2; ++c) {
        const float* zbuf = sz[c & 1];
        for (int tt = 0; tt < 256; ++tt) {
            if (cons) {
                const int t = (c << 8) + tt;
                const float* hr = shp[t & 1];
                float*       hw = shp[(t + 1) & 1];

                const f32x4 z4 = *(const f32x4*)(zbuf + tt * MIXD + o * 4);
                const f32x4 h0 = *(const f32x4*)(hr + o * 12);
                const f32x4 h1 = *(const f32x4*)(hr + o * 12 + 4);
                const f32x4 h2 = *(const f32x4*)(hr + o * 12 + 8);
                const f32x2 hh[6] = { h0.xy, h0.zw, h1.xy, h1.zw, h2.xy, h2.zw };

                float hv[3];
                #pragma unroll
                for (int i = 0; i < 3; ++i) {
                    f32x2 aR  = {br[i],  0.f}, aU  = {bu[i],  0.f};
                    f32x2 aXN = {bxn[i], 0.f}, aHN = {bhn[i], 0.f};

                    aR  = __builtin_elementwise_fma(wir[i][0], z4.xy, aR);
                    aR  = __builtin_elementwise_fma(wir[i][1], z4.zw, aR);
                    aU  = __builtin_elementwise_fma(wiu[i][0], z4.xy, aU);
                    aU  = __builtin_elementwise_fma(wiu[i][1], z4.zw, aU);
                    aXN = __builtin_elementwise_fma(win[i][0], z4.xy, aXN);
                    aXN = __builtin_elementwise_fma(win[i][1], z4.zw, aXN);

                    #pragma unroll
                    for (int k = 0; k < 6; ++k) {
                        aR  = __builtin_elementwise_fma(whr[i][k], hh[k], aR);
                        aU  = __builtin_elementwise_fma(whu[i][k], hh[k], aU);
                        aHN = __builtin_elementwise_fma(whn[i][k], hh[k], aHN);
                    }

                    float sR  = octet_reduce_lane0(aR.x  + aR.y);
                    float sU  = octet_reduce_lane0(aU.x  + aU.y);
                    float sXN = octet_reduce_lane0(aXN.x + aXN.y);
                    float sHN = octet_reduce_lane0(aHN.x + aHN.y);

                    float r = __builtin_amdgcn_rcpf(1.f + EXP2(-sR));
                    float u = __builtin_amdgcn_rcpf(1.f + EXP2(-sU));
                    float n = 1.f - 2.f * __builtin_amdgcn_rcpf(1.f + EXP2(sXN + r * sHN));
                    hv[i] = u * (hown[i] - n) + n;   // lane0 correct; others garbage
                    hown[i] = hv[i];
                }
                if (o == 0) {
                    hw[j0]      = hv[0];
                    hw[j0 + 32] = hv[1];
                    hw[j0 + 64] = hv[2];
                }
            } else if (c == 0) {
                // produce row tt of chunk 1 (t = 256+tt) into sz[1]
                const float* xr = x + ((size_t)b * TT + 256 + tt) * IDIM + 64 * pks;
                f32x4 xv[16];
                #pragma unroll
                for (int u = 0; u < 16; ++u) xv[u] = *(const f32x4*)(xr + 4 * u);
                f32x2 acc = {0.f, 0.f};
                #pragma unroll
                for (int u = 0; u < 16; ++u) {
                    acc = __builtin_elementwise_fma(wp[2*u],   xv[u].xy, acc);
                    acc = __builtin_elementwise_fma(wp[2*u+1], xv[u].zw, acc);
                }
                float s = octet_reduce_lane0(acc.x + acc.y);
                if (pks == 0) sz[1][tt * MIXD + pm] = s;
            }
            __syncthreads();   // h exchange + produced-row visibility
        }
    }

    // ---- fused head: zn = Whead @ h + bhead ; y = zn @ Wmix ----
    if (tid < MIXD) {
        const float* h = shp[0];                 // TT even -> final h in shp[0]
        float a0 = 0.f, a1 = 0.f, a2 = 0.f, a3 = 0.f;
        #pragma unroll
        for (int kc = 0; kc < HID / 4; ++kc) {
            f32x4 wv = *(const f32x4*)(Whead + (size_t)tid * HID + kc * 4);
            f32x4 hv4 = *(const f32x4*)(h + kc * 4);
            a0 += wv.x * hv4.x; a1 += wv.y * hv4.y;
            a2 += wv.z * hv4.z; a3 += wv.w * hv4.w;
        }
        szn[tid] = bhead[tid] + ((a0 + a1) + (a2 + a3));
    }
    __syncthreads();
    {
        const int col = tid;                     // 512 threads = 512 cols
        float acc = 0.f;
        #pragma unroll
        for (int m = 0; m < MIXD; ++m)
            acc += szn[m] * Wmix[(size_t)m * IDIM + col];
        y[(size_t)b * IDIM + col] = acc;
    }
}

extern "C" void kernel_launch(void* const* d_in, const int* in_sizes, int n_in,
                              void* d_out, int out_size, void* d_ws, size_t ws_size,
                              hipStream_t stream) {
    const float* x     = (const float*)d_in[0];
    const float* Wmix  = (const float*)d_in[1];
    const float* Wih   = (const float*)d_in[2];
    const float* Whh   = (const float*)d_in[3];
    const float* bih   = (const float*)d_in[4];
    const float* bhh   = (const float*)d_in[5];
    const float* Whead = (const float*)d_in[6];
    const float* bhead = (const float*)d_in[7];
    float* out = (float*)d_out;

    k_fused<<<BB, 512, 0, stream>>>(x, Wmix, Wih, Whh, bih, bhh, Whead, bhead, out);
}